// Round 4
// baseline (937.357 us; speedup 1.0000x reference)
//
#include <hip/hip_runtime.h>
#include <cstddef>

#define NQ 4
#define KCODES 1024
#define CD 8
#define DIM 512
#define BATCH 16
#define TLEN 4096

// d_out layout (floats)
#define OUT_ZQ 0
#define OUT_CODES ((size_t)BATCH * DIM * TLEN)
#define OUT_LOSS (OUT_CODES + (size_t)NQ * BATCH * TLEN)

// workspace layout (float offsets)
#define WS_WT 0                        // w_in^T  [512][32] fp32 (col i*8+o)
#define WS_WC 16384                    // w_out   [512][32] fp32 (col j*8+oo)
#define WS_CN 32768                    // normalized codebooks [4][1024][8] fp32
#define WS_M64 65536                   // M [4][4][8][8] double (=2048 floats)
#define WS_CC64 67584                  // cc [4][8] double (=64 floats)
#define WS_BS 67648                    // bsum [512] fp32
#define WS_P  68160                    // P  [B*T][32] fp32
#define WS_ZR (WS_P + (size_t)BATCH * TLEN * 32)   // zrot32 [B*T][32]
// total = 4,262,464 floats = 17.05 MB

__global__ void rvq_zero(float* out) {
  out[OUT_LOSS] = 0.f;
  out[OUT_LOSS + 1] = 0.f;
}

// ---- prep1: weight-norm (fp64 norms) + layout transforms + codebook normalize
__global__ void rvq_prep1(const float* __restrict__ inv, const float* __restrict__ ing,
                          const float* __restrict__ outv, const float* __restrict__ outg,
                          const float* __restrict__ cb, float* __restrict__ ws) {
  const int blk = blockIdx.x, tid = threadIdx.x;
  if (blk < 32) {
    // in_proj rows: (i,o), length 512
    const int i = blk >> 3, o = blk & 7;
    const float* v = inv + (size_t)(i * CD + o) * DIM;
    const float a = v[tid], b = v[tid + 256];
    double s = (double)a * a + (double)b * b;
    #pragma unroll
    for (int off = 32; off >= 1; off >>= 1) s += __shfl_xor(s, off);
    __shared__ double red[4];
    if ((tid & 63) == 0) red[tid >> 6] = s;
    __syncthreads();
    const double nrm = fmax(sqrt(red[0] + red[1] + red[2] + red[3]), 1e-12);
    const double g = (double)ing[i * CD + o];
    ws[WS_WT + (size_t)tid * 32 + i * 8 + o] = (float)(g * a / nrm);
    ws[WS_WT + (size_t)(tid + 256) * 32 + i * 8 + o] = (float)(g * b / nrm);
  } else {
    const int rid = (blk - 32) * 256 + tid;   // 0..6143
    if (rid < NQ * DIM) {
      // out_proj rows: rid = j*512 + d
      const int j = rid >> 9, d = rid & 511;
      const float* v = outv + (size_t)rid * CD;
      float vv[8]; double n2 = 0.0;
      #pragma unroll
      for (int o = 0; o < 8; ++o) { vv[o] = v[o]; n2 += (double)vv[o] * vv[o]; }
      const double nrm = fmax(sqrt(n2), 1e-12);
      const double g = (double)outg[rid];
      #pragma unroll
      for (int o = 0; o < 8; ++o)
        ws[WS_WC + (size_t)d * 32 + j * 8 + o] = (float)(g * vv[o] / nrm);
    } else {
      // codebook rows
      const int k = rid - NQ * DIM;   // 0..4095
      const float* v = cb + (size_t)k * CD;
      float vv[8]; double n2 = 0.0;
      #pragma unroll
      for (int o = 0; o < 8; ++o) { vv[o] = v[o]; n2 += (double)vv[o] * vv[o]; }
      const double nrm = fmax(sqrt(n2), 1e-12);
      #pragma unroll
      for (int o = 0; o < 8; ++o)
        ws[WS_CN + (size_t)k * 8 + o] = (float)(vv[o] / nrm);
    }
  }
}

// ---- prep2: M (fp64), cc (fp64), bsum
__global__ void rvq_prep2(const float* __restrict__ inb, const float* __restrict__ outb,
                          float* __restrict__ ws) {
  double* m64  = (double*)(ws + WS_M64);
  double* cc64 = (double*)(ws + WS_CC64);
  const int gid = blockIdx.x * 256 + threadIdx.x;   // 0..2047
  if (gid < 1024) {
    const int i = gid >> 8, j = (gid >> 6) & 3, o = (gid >> 3) & 7, oo = gid & 7;
    double m = 0.0;
    if (j < i) {
      const float* wt = ws + WS_WT + i * 8 + o;
      const float* wc = ws + WS_WC + j * 8 + oo;
      for (int d = 0; d < DIM; ++d)
        m += (double)wt[(size_t)d * 32] * (double)wc[(size_t)d * 32];
    }
    m64[gid] = m;
  } else if (gid < 1056) {
    const int t2 = gid - 1024, i = t2 >> 3, o = t2 & 7;
    double c = (double)inb[i * CD + o];
    const float* wt = ws + WS_WT + i * 8 + o;
    for (int j = 0; j < i; ++j) {
      const float* bo = outb + (size_t)j * DIM;
      double s = 0.0;
      for (int d = 0; d < DIM; ++d) s += (double)wt[(size_t)d * 32] * (double)bo[d];
      c -= s;
    }
    cc64[t2] = c;
  } else if (gid < 1568) {
    const int d = gid - 1056;
    float s = 0.f;
    #pragma unroll
    for (int j = 0; j < NQ; ++j) s += outb[(size_t)j * DIM + d];
    ws[WS_BS + d] = s;
  }
}

// ---- K2: P = W_in_all · z. fp32 FMA in 32-elem chunks, fp64 chunk combine.
__launch_bounds__(256)
__global__ void rvq_inproj(const float* __restrict__ z, const float* __restrict__ wsc,
                           float* __restrict__ ws) {
  const int blk = blockIdx.x, tid = threadIdx.x;
  const int b = blk >> 5, t0 = (blk & 31) * 128;
  const int hid = tid >> 7, t = tid & 127;       // hid wave-uniform
  const float* zp = z + (size_t)b * DIM * TLEN + t0 + t;
  const float* wt = wsc + WS_WT + hid * 16;
  double a64[16];
  #pragma unroll
  for (int o = 0; o < 16; ++o) a64[o] = 0.0;
  for (int c = 0; c < 16; ++c) {
    float a32[16];
    #pragma unroll
    for (int o = 0; o < 16; ++o) a32[o] = 0.f;
    #pragma unroll 8
    for (int dd = 0; dd < 32; ++dd) {
      const int d = c * 32 + dd;
      const float zv = zp[(size_t)d * TLEN];
      #pragma unroll
      for (int o = 0; o < 16; ++o) a32[o] += wt[(size_t)d * 32 + o] * zv;
    }
    #pragma unroll
    for (int o = 0; o < 16; ++o) a64[o] += (double)a32[o];
  }
  float* pw = ws + WS_P + ((size_t)b * TLEN + t0 + t) * 32 + hid * 16;
  #pragma unroll
  for (int q = 0; q < 4; ++q)
    *(float4*)(pw + q * 4) = make_float4((float)a64[q*4], (float)a64[q*4+1],
                                         (float)a64[q*4+2], (float)a64[q*4+3]);
}

// ---- K3: latent VQ, 1 thread = 1 token. fp64 e/rotation/propagation; fp32 scan.
__launch_bounds__(256)
__global__ void rvq_latent(const float* __restrict__ cb, const float* __restrict__ wsc,
                           float* __restrict__ ws, float* __restrict__ out) {
  const int blk = blockIdx.x, tid = threadIdx.x;
  const int b = blk >> 4, t0 = (blk & 15) * 256;
  const size_t g = (size_t)b * TLEN + t0 + tid;
  const double* m64  = (const double*)(wsc + WS_M64);
  const double* cc64 = (const double*)(wsc + WS_CC64);

  double p64[32];
  {
    const float* pp = ws + WS_P + g * 32;
    #pragma unroll
    for (int q = 0; q < 8; ++q) {
      const float4 v = *(const float4*)(pp + q * 4);
      p64[q*4] = v.x; p64[q*4+1] = v.y; p64[q*4+2] = v.z; p64[q*4+3] = v.w;
    }
  }
  double loss64 = 0.0;

  #pragma unroll
  for (int i = 0; i < NQ; ++i) {
    float e32[8];
    #pragma unroll
    for (int o = 0; o < 8; ++o) e32[o] = (float)(p64[i * 8 + o] + cc64[i * 8 + o]);

    // fp32 normalize with true divide (mimic reference)
    float ne2f = 0.f;
    #pragma unroll
    for (int o = 0; o < 8; ++o) ne2f += e32[o] * e32[o];
    const float den = fmaxf(sqrtf(ne2f), 1e-12f);
    float en[8];
    #pragma unroll
    for (int o = 0; o < 8; ++o) en[o] = e32[o] / den;

    // argmax over 1024 codes; cn uniform -> scalar loads
    const float* cn = wsc + WS_CN + (size_t)i * KCODES * 8;
    float best = -1e30f; int bk = 0;
    for (int k0 = 0; k0 < KCODES; k0 += 4) {
      float s0 = 0.f, s1 = 0.f, s2 = 0.f, s3 = 0.f;
      const float* c0 = cn + (size_t)k0 * 8;
      #pragma unroll
      for (int o = 0; o < 8; ++o) {
        s0 += c0[o]      * en[o];
        s1 += c0[8 + o]  * en[o];
        s2 += c0[16 + o] * en[o];
        s3 += c0[24 + o] * en[o];
      }
      if (s0 > best) { best = s0; bk = k0; }
      if (s1 > best) { best = s1; bk = k0 + 1; }
      if (s2 > best) { best = s2; bk = k0 + 2; }
      if (s3 > best) { best = s3; bk = k0 + 3; }
    }
    out[OUT_CODES + (size_t)(i * BATCH + b) * TLEN + t0 + tid] = (float)bk;

    // raw code vector (divergent gather, L2-hot)
    float qv[8];
    {
      const float* qp = cb + (size_t)(i * KCODES + bk) * 8;
      const float4 q0 = *(const float4*)qp;
      const float4 q1 = *(const float4*)(qp + 4);
      qv[0]=q0.x; qv[1]=q0.y; qv[2]=q0.z; qv[3]=q0.w;
      qv[4]=q1.x; qv[5]=q1.y; qv[6]=q1.z; qv[7]=q1.w;
    }
    // loss (fp64 accumulate)
    #pragma unroll
    for (int o = 0; o < 8; ++o) {
      const double d2 = (double)e32[o] - (double)qv[o];
      loss64 += d2 * d2;
    }
    // rotation trick in fp64 (inputs are the fp32 e, q like the reference)
    double ne64 = 0.0, nq64 = 0.0;
    #pragma unroll
    for (int o = 0; o < 8; ++o) {
      ne64 += (double)e32[o] * e32[o];
      nq64 += (double)qv[o] * qv[o];
    }
    const double ne_d = sqrt(ne64), nq_d = sqrt(nq64);
    const double rne = 1.0 / fmax(ne_d, 1e-12);
    const double rq  = 1.0 / fmax(nq_d, 1e-12);
    double ru[8]; double nr2 = 0.0;
    #pragma unroll
    for (int o = 0; o < 8; ++o) {
      ru[o] = (double)e32[o] * rne + (double)qv[o] * rq;
      nr2 += ru[o] * ru[o];
    }
    const double rr = 1.0 / fmax(sqrt(nr2), 1e-12);
    const double scale = nq_d / fmax(ne_d, 1e-8);
    double re = 0.0;
    #pragma unroll
    for (int o = 0; o < 8; ++o) { ru[o] *= rr; re += ru[o] * (double)e32[o]; }
    const double ene = ne64 * rne;
    double zr64[8];
    #pragma unroll
    for (int o = 0; o < 8; ++o)
      zr64[o] = scale * ((double)e32[o] - 2.0 * ru[o] * re + 2.0 * ((double)qv[o] * rq) * ene);

    // store zrot (fp32 for K4)
    {
      float* zw = ws + WS_ZR + g * 32 + i * 8;
      *(float4*)zw       = make_float4((float)zr64[0], (float)zr64[1], (float)zr64[2], (float)zr64[3]);
      *(float4*)(zw + 4) = make_float4((float)zr64[4], (float)zr64[5], (float)zr64[6], (float)zr64[7]);
    }
    // propagate (fp64): p(i2) -= M(i2,i) · zr
    #pragma unroll
    for (int i2 = i + 1; i2 < NQ; ++i2) {
      const double* mp = m64 + (size_t)(i2 * 4 + i) * 64;
      #pragma unroll
      for (int o = 0; o < 8; ++o) {
        double s = 0.0;
        #pragma unroll
        for (int oo = 0; oo < 8; ++oo) s += mp[o * 8 + oo] * zr64[oo];
        p64[i2 * 8 + o] -= s;
      }
    }
  }

  // loss reduce per wave + atomics
  #pragma unroll
  for (int off = 32; off >= 1; off >>= 1) loss64 += __shfl_xor(loss64, off);
  if ((tid & 63) == 0) {
    const float lv = (float)(loss64 * (1.0 / ((double)CD * TLEN * BATCH)));
    atomicAdd(out + OUT_LOSS, lv);
    atomicAdd(out + OUT_LOSS + 1, lv);
  }
}

// ---- K4: z_q[b][d][t] = bsum[d] + W_cat[d][:] · zrot[b][t][:]
__launch_bounds__(256)
__global__ void rvq_outproj(const float* __restrict__ wsc, const float* __restrict__ ws,
                            float* __restrict__ out) {
  const int blk = blockIdx.x, tid = threadIdx.x;
  const int b = blk >> 5, rem = blk & 31;
  const int d0 = (rem >> 3) * 128, t0 = (rem & 7) * 512;
  const int t = t0 + 2 * tid;
  const size_t g = (size_t)b * TLEN + t;

  float za[32], zb2[32];
  {
    const float* zp = ws + WS_ZR + g * 32;
    #pragma unroll
    for (int q = 0; q < 8; ++q) {
      const float4 v = *(const float4*)(zp + q * 4);
      za[q*4] = v.x; za[q*4+1] = v.y; za[q*4+2] = v.z; za[q*4+3] = v.w;
      const float4 w = *(const float4*)(zp + 32 + q * 4);
      zb2[q*4] = w.x; zb2[q*4+1] = w.y; zb2[q*4+2] = w.z; zb2[q*4+3] = w.w;
    }
  }
  const float* wc = wsc + WS_WC;
  const float* bs = wsc + WS_BS;
  float* ob = out + OUT_ZQ + (size_t)b * DIM * TLEN + t;
  #pragma unroll 2
  for (int dr = 0; dr < 128; ++dr) {
    const int d = d0 + dr;
    const float* wp = wc + (size_t)d * 32;
    float a0 = bs[d], a1 = a0;
    #pragma unroll
    for (int o = 0; o < 32; ++o) {
      const float w = wp[o];
      a0 += w * za[o];
      a1 += w * zb2[o];
    }
    *(float2*)(ob + (size_t)d * TLEN) = make_float2(a0, a1);
  }
}

extern "C" void kernel_launch(void* const* d_in, const int* in_sizes, int n_in,
                              void* d_out, int out_size, void* d_ws, size_t ws_size,
                              hipStream_t stream) {
  const float* z    = (const float*)d_in[0];
  const float* inv  = (const float*)d_in[1];
  const float* ing  = (const float*)d_in[2];
  const float* inb  = (const float*)d_in[3];
  const float* outv = (const float*)d_in[4];
  const float* outg = (const float*)d_in[5];
  const float* outb = (const float*)d_in[6];
  const float* cbp  = (const float*)d_in[7];
  float* out = (float*)d_out;
  float* ws  = (float*)d_ws;

  hipLaunchKernelGGL(rvq_zero,   dim3(1),   dim3(1),   0, stream, out);
  hipLaunchKernelGGL(rvq_prep1,  dim3(56),  dim3(256), 0, stream, inv, ing, outv, outg, cbp, ws);
  hipLaunchKernelGGL(rvq_prep2,  dim3(8),   dim3(256), 0, stream, inb, outb, ws);
  hipLaunchKernelGGL(rvq_inproj, dim3(512), dim3(256), 0, stream, z, ws, ws);
  hipLaunchKernelGGL(rvq_latent, dim3(256), dim3(256), 0, stream, cbp, ws, ws, out);
  hipLaunchKernelGGL(rvq_outproj,dim3(512), dim3(256), 0, stream, ws, ws, out);
}